// Round 1
// baseline (589.270 us; speedup 1.0000x reference)
//
#include <hip/hip_runtime.h>
#include <hip/hip_bf16.h>
#include <math.h>

#define BATCH  64
#define SEQ    2048
#define DMODEL 512
#define ATT    256
#define M_TOTAL (BATCH * SEQ)

#define MT   64    // positions per block in scores kernel
#define KC   32    // k-chunk staged in LDS
#define XPAD 36    // row pad (dwords): 2-way-max bank aliasing, 16B-aligned rows
#define WPAD 36

// K1: z[m] = sum_a tanh(dot(X[m,:], Wa[a,:]) + ba[a]) * ae[a]
// Block: 256 threads, 64 positions x 256 att-units.
// Thread tile: 4 positions (pg = tid>>4) x 16 att-units (a = j*16 + ag, ag = tid&15).
__global__ __launch_bounds__(256, 3)
void scores_kernel(const float* __restrict__ X, const float* __restrict__ Wa,
                   const float* __restrict__ ba, const float* __restrict__ ae,
                   float* __restrict__ z) {
    __shared__ float xs[MT][XPAD];
    __shared__ float wsh[ATT][WPAD];
    const int tid = threadIdx.x;
    const int m0  = blockIdx.x * MT;
    const int ag  = tid & 15;
    const int pg  = tid >> 4;

    float acc[4][16];
    #pragma unroll
    for (int i = 0; i < 4; ++i)
        #pragma unroll
        for (int j = 0; j < 16; ++j) acc[i][j] = 0.f;

    for (int kc = 0; kc < DMODEL / KC; ++kc) {
        __syncthreads();
        // stage X tile [MT][KC]: 512 float4 slots, 2 per thread
        #pragma unroll
        for (int i = 0; i < 2; ++i) {
            int s = tid + i * 256;
            int r = s >> 3, c = (s & 7) * 4;
            *(float4*)&xs[r][c] =
                *(const float4*)&X[(size_t)(m0 + r) * DMODEL + kc * KC + c];
        }
        // stage Wa tile [ATT][KC]: 2048 float4 slots, 8 per thread
        #pragma unroll
        for (int i = 0; i < 8; ++i) {
            int s = tid + i * 256;
            int r = s >> 3, c = (s & 7) * 4;
            *(float4*)&wsh[r][c] =
                *(const float4*)&Wa[(size_t)r * DMODEL + kc * KC + c];
        }
        __syncthreads();

        #pragma unroll
        for (int k4 = 0; k4 < KC / 4; ++k4) {
            float4 xv[4];
            #pragma unroll
            for (int i = 0; i < 4; ++i)
                xv[i] = *(const float4*)&xs[pg * 4 + i][k4 * 4];
            #pragma unroll
            for (int j = 0; j < 16; ++j) {
                float4 wv = *(const float4*)&wsh[j * 16 + ag][k4 * 4];
                #pragma unroll
                for (int i = 0; i < 4; ++i) {
                    acc[i][j] = fmaf(xv[i].x, wv.x, acc[i][j]);
                    acc[i][j] = fmaf(xv[i].y, wv.y, acc[i][j]);
                    acc[i][j] = fmaf(xv[i].z, wv.z, acc[i][j]);
                    acc[i][j] = fmaf(xv[i].w, wv.w, acc[i][j]);
                }
            }
        }
    }

    // epilogue: z-partial = sum_j tanh(acc + ba) * ae, reduce over 16 ag-lanes
    float zp[4] = {0.f, 0.f, 0.f, 0.f};
    #pragma unroll
    for (int j = 0; j < 16; ++j) {
        int a = j * 16 + ag;
        float bav = ba[a], aev = ae[a];
        #pragma unroll
        for (int i = 0; i < 4; ++i)
            zp[i] += tanhf(acc[i][j] + bav) * aev;
    }
    #pragma unroll
    for (int off = 8; off >= 1; off >>= 1)
        #pragma unroll
        for (int i = 0; i < 4; ++i)
            zp[i] += __shfl_xor(zp[i], off, 64);
    if (ag == 0) {
        #pragma unroll
        for (int i = 0; i < 4; ++i)
            z[m0 + pg * 4 + i] = zp[i];
    }
}

// K2: in-place softmax over SEQ per batch. One block per batch.
__global__ __launch_bounds__(256)
void softmax_kernel(float* __restrict__ zw) {
    __shared__ float red[4];
    __shared__ float bcast;
    const int b = blockIdx.x, tid = threadIdx.x;
    float* row = zw + (size_t)b * SEQ;

    float zi[8];
    #pragma unroll
    for (int i = 0; i < 8; ++i) zi[i] = row[tid + i * 256];

    float m = -3.0e38f;
    #pragma unroll
    for (int i = 0; i < 8; ++i) m = fmaxf(m, zi[i]);
    #pragma unroll
    for (int off = 32; off >= 1; off >>= 1) m = fmaxf(m, __shfl_xor(m, off, 64));
    if ((tid & 63) == 0) red[tid >> 6] = m;
    __syncthreads();
    if (tid == 0) bcast = fmaxf(fmaxf(red[0], red[1]), fmaxf(red[2], red[3]));
    __syncthreads();
    m = bcast;

    float s = 0.f;
    #pragma unroll
    for (int i = 0; i < 8; ++i) { zi[i] = expf(zi[i] - m); s += zi[i]; }
    #pragma unroll
    for (int off = 32; off >= 1; off >>= 1) s += __shfl_xor(s, off, 64);
    __syncthreads();
    if ((tid & 63) == 0) red[tid >> 6] = s;
    __syncthreads();
    if (tid == 0) bcast = 1.f / (red[0] + red[1] + red[2] + red[3]);
    __syncthreads();
    float inv = bcast;

    #pragma unroll
    for (int i = 0; i < 8; ++i) row[tid + i * 256] = zi[i] * inv;
}

// K3: att_aggr[b][f] += sum_s X[b][s][f] * w[b][s], 4 s-chunks per batch.
__global__ __launch_bounds__(512)
void pool_kernel(const float* __restrict__ X, const float* __restrict__ w,
                 float* __restrict__ out) {
    __shared__ float wl[512];
    const int b  = blockIdx.y;
    const int sc = blockIdx.x;       // 0..3
    const int f  = threadIdx.x;      // 0..511
    const int s0 = sc * 512;
    wl[f] = w[(size_t)b * SEQ + s0 + f];
    __syncthreads();
    const float* xp = X + ((size_t)b * SEQ + s0) * DMODEL + f;
    float acc = 0.f;
    #pragma unroll 8
    for (int s = 0; s < 512; ++s)
        acc = fmaf(xp[(size_t)s * DMODEL], wl[s], acc);
    atomicAdd(&out[b * DMODEL + f], acc);
}

extern "C" void kernel_launch(void* const* d_in, const int* in_sizes, int n_in,
                              void* d_out, int out_size, void* d_ws, size_t ws_size,
                              hipStream_t stream) {
    const float* X  = (const float*)d_in[0];
    const float* Wa = (const float*)d_in[1];
    const float* ba = (const float*)d_in[2];
    const float* ae = (const float*)d_in[3];
    float* out  = (float*)d_out;
    float* feat = out;                       // [64][512]
    float* wgt  = out + BATCH * DMODEL;      // [64][2048]; holds z pre-softmax

    scores_kernel<<<M_TOTAL / MT, 256, 0, stream>>>(X, Wa, ba, ae, wgt);
    softmax_kernel<<<BATCH, 256, 0, stream>>>(wgt);
    hipMemsetAsync(feat, 0, BATCH * DMODEL * sizeof(float), stream);
    pool_kernel<<<dim3(4, BATCH), 512, 0, stream>>>(X, wgt, feat);
}

// Round 2
// 166.570 us; speedup vs baseline: 3.5377x; 3.5377x over previous
//
#include <hip/hip_runtime.h>
#include <hip/hip_bf16.h>
#include <math.h>

#define BATCH  64
#define SEQ    2048
#define DMODEL 512
#define ATT    256
#define M_TOTAL (BATCH * SEQ)

#define MT 64                       // rows per block (scores GEMM)
#define KC 32                       // k per chunk
#define NCHUNK (DMODEL / KC)        // 16
#define BPAD 40                     // padded LDS row stride in ushorts (80 B)
#define WA_CHUNK_ELEMS (ATT * BPAD) // 10240 ushorts per chunk image
#define WA_LO_OFF (NCHUNK * WA_CHUNK_ELEMS)

typedef __attribute__((ext_vector_type(8))) short short8v;
typedef __attribute__((ext_vector_type(4))) float floatx4;

__device__ __forceinline__ ushort f2bf_rne(float f) {
    unsigned u = __float_as_uint(f);
    u += 0x7FFFu + ((u >> 16) & 1u);
    return (ushort)(u >> 16);
}
__device__ __forceinline__ float bf2f(ushort h) {
    return __uint_as_float(((unsigned)h) << 16);
}
__device__ __forceinline__ float fast_tanh(float x) {
    float ax = fabsf(x);
    float e  = __expf(ax + ax);                       // e^{2|x|}, inf ok
    float t  = 1.0f - 2.0f * __builtin_amdgcn_rcpf(e + 1.0f);
    return copysignf(t, x);
}
__device__ __forceinline__ void gll16(const void* g, void* l) {
    __builtin_amdgcn_global_load_lds(
        (const __attribute__((address_space(1))) unsigned*)g,
        (__attribute__((address_space(3))) unsigned*)l, 16, 0, 0);
}
__device__ __forceinline__ void cvt_store(float4 v, ushort* hp, ushort* lp) {
    ushort4 h, lo;
    h.x = f2bf_rne(v.x); lo.x = f2bf_rne(v.x - bf2f(h.x));
    h.y = f2bf_rne(v.y); lo.y = f2bf_rne(v.y - bf2f(h.y));
    h.z = f2bf_rne(v.z); lo.z = f2bf_rne(v.z - bf2f(h.z));
    h.w = f2bf_rne(v.w); lo.w = f2bf_rne(v.w - bf2f(h.w));
    *(ushort4*)hp = h; *(ushort4*)lp = lo;
}

// K0: Wa fp32 [256][512] -> bf16 hi/lo, laid out as pre-padded per-chunk LDS
// images so the GEMM can stage B with linear global_load_lds.
__global__ __launch_bounds__(256)
void wa_convert_kernel(const float* __restrict__ Wa, ushort* __restrict__ out) {
    int idx = blockIdx.x * 256 + threadIdx.x;   // 131072 total
    float x = Wa[idx];
    ushort hi = f2bf_rne(x);
    ushort lo = f2bf_rne(x - bf2f(hi));
    int a = idx >> 9, k = idx & 511;
    int kc = k >> 5, kk = k & 31;
    size_t o = (size_t)kc * WA_CHUNK_ELEMS + (size_t)a * BPAD + kk;
    out[o] = hi;
    out[WA_LO_OFF + o] = lo;
}

// K1: z[m] = sum_a tanh(X[m]·Wa[a] + ba[a]) * ae[a]  via split-bf16 MFMA.
// Block: 256 thr / 4 waves, tile 64(M) x 256(A). Wave w owns cols [w*64,w*64+64).
__global__ __launch_bounds__(256, 3)
void scores_mfma_kernel(const float* __restrict__ X,
                        const ushort* __restrict__ wa_cvt,
                        const float* __restrict__ ba,
                        const float* __restrict__ ae,
                        float* __restrict__ z) {
    __shared__ ushort a_hi[MT * BPAD];
    __shared__ ushort a_lo[MT * BPAD];
    __shared__ ushort b_hi[ATT * BPAD];
    __shared__ ushort b_lo[ATT * BPAD];
    __shared__ float  zbuf[4][MT];

    const int tid = threadIdx.x;
    const int l   = tid & 63;
    const int wid = tid >> 6;
    const int n   = l & 15;
    const int g   = l >> 4;          // 0..3 k-group
    const int m0  = blockIdx.x * MT;

    // X staging slots: 512 float4 slots, 2 per thread; slot s -> r=s>>3, c4=s&7
    const int r0 = tid >> 3,         c40 = tid & 7;
    const int r1 = (tid + 256) >> 3, c41 = tid & 7;
    const float* xp0 = X + (size_t)(m0 + r0) * DMODEL + c40 * 4;
    const float* xp1 = X + (size_t)(m0 + r1) * DMODEL + c41 * 4;

    floatx4 acc[4][4];
    #pragma unroll
    for (int i = 0; i < 4; ++i)
        #pragma unroll
        for (int j = 0; j < 4; ++j)
            acc[i][j] = (floatx4){0.f, 0.f, 0.f, 0.f};

    float4 xa = *(const float4*)xp0;   // prefetch chunk 0
    float4 xb = *(const float4*)xp1;

    for (int kc = 0; kc < NCHUNK; ++kc) {
        __syncthreads();   // previous chunk's compute done; LDS free
        // B: direct global->LDS copy of the pre-padded chunk image (L2-hot)
        {
            const char* ghi = (const char*)(wa_cvt + (size_t)kc * WA_CHUNK_ELEMS);
            const char* glo = (const char*)(wa_cvt + WA_LO_OFF + (size_t)kc * WA_CHUNK_ELEMS);
            #pragma unroll
            for (int i = 0; i < 5; ++i) {
                int seg = wid * 5 + i;             // 20 segs of 1024 B per half
                gll16(ghi + seg * 1024 + l * 16, (char*)b_hi + seg * 1024);
                gll16(glo + seg * 1024 + l * 16, (char*)b_lo + seg * 1024);
            }
        }
        // A: split prefetched X regs into hi/lo bf16, store padded
        cvt_store(xa, &a_hi[r0 * BPAD + c40 * 4], &a_lo[r0 * BPAD + c40 * 4]);
        cvt_store(xb, &a_hi[r1 * BPAD + c41 * 4], &a_lo[r1 * BPAD + c41 * 4]);
        __syncthreads();   // drains gll (vmcnt) + A writes (lgkm)

        // prefetch next X chunk: latency hides under MFMA compute
        if (kc + 1 < NCHUNK) {
            xa = *(const float4*)(xp0 + (kc + 1) * KC);
            xb = *(const float4*)(xp1 + (kc + 1) * KC);
        }

        // fragments: rows of row-major (m,k)/(n,k) tiles, identical k-index math
        short8v ah[4], av[4], bh[4], bv[4];
        #pragma unroll
        for (int mi = 0; mi < 4; ++mi) {
            ah[mi] = *(const short8v*)&a_hi[(mi * 16 + n) * BPAD + g * 8];
            av[mi] = *(const short8v*)&a_lo[(mi * 16 + n) * BPAD + g * 8];
        }
        #pragma unroll
        for (int nj = 0; nj < 4; ++nj) {
            int brow = wid * 64 + nj * 16 + n;
            bh[nj] = *(const short8v*)&b_hi[brow * BPAD + g * 8];
            bv[nj] = *(const short8v*)&b_lo[brow * BPAD + g * 8];
        }
        #pragma unroll
        for (int mi = 0; mi < 4; ++mi)
            #pragma unroll
            for (int nj = 0; nj < 4; ++nj) {
                acc[mi][nj] = __builtin_amdgcn_mfma_f32_16x16x32_bf16(ah[mi], bh[nj], acc[mi][nj], 0, 0, 0);
                acc[mi][nj] = __builtin_amdgcn_mfma_f32_16x16x32_bf16(ah[mi], bv[nj], acc[mi][nj], 0, 0, 0);
                acc[mi][nj] = __builtin_amdgcn_mfma_f32_16x16x32_bf16(av[mi], bh[nj], acc[mi][nj], 0, 0, 0);
            }
    }

    // epilogue: tanh + ae-weighted reduce over ATT. C/D map (m89-verified):
    // col = lane&15, row = (lane>>4)*4 + reg
    float bav[4], aev[4];
    #pragma unroll
    for (int nj = 0; nj < 4; ++nj) {
        int a_col = wid * 64 + nj * 16 + n;
        bav[nj] = ba[a_col];
        aev[nj] = ae[a_col];
    }
    #pragma unroll
    for (int mi = 0; mi < 4; ++mi) {
        float zp0 = 0.f, zp1 = 0.f, zp2 = 0.f, zp3 = 0.f;
        #pragma unroll
        for (int nj = 0; nj < 4; ++nj) {
            zp0 += fast_tanh(acc[mi][nj].x + bav[nj]) * aev[nj];
            zp1 += fast_tanh(acc[mi][nj].y + bav[nj]) * aev[nj];
            zp2 += fast_tanh(acc[mi][nj].z + bav[nj]) * aev[nj];
            zp3 += fast_tanh(acc[mi][nj].w + bav[nj]) * aev[nj];
        }
        #pragma unroll
        for (int off = 8; off >= 1; off >>= 1) {
            zp0 += __shfl_xor(zp0, off, 64);
            zp1 += __shfl_xor(zp1, off, 64);
            zp2 += __shfl_xor(zp2, off, 64);
            zp3 += __shfl_xor(zp3, off, 64);
        }
        if (n == 0)
            *(float4*)&zbuf[wid][mi * 16 + g * 4] = make_float4(zp0, zp1, zp2, zp3);
    }
    __syncthreads();
    if (tid < MT)
        z[m0 + tid] = zbuf[0][tid] + zbuf[1][tid] + zbuf[2][tid] + zbuf[3][tid];
}

// K2: in-place softmax over SEQ per batch. One block per batch.
__global__ __launch_bounds__(256)
void softmax_kernel(float* __restrict__ zw) {
    __shared__ float red[4];
    __shared__ float bcast;
    const int b = blockIdx.x, tid = threadIdx.x;
    float* row = zw + (size_t)b * SEQ;

    float zi[8];
    #pragma unroll
    for (int i = 0; i < 8; ++i) zi[i] = row[tid + i * 256];

    float m = -3.0e38f;
    #pragma unroll
    for (int i = 0; i < 8; ++i) m = fmaxf(m, zi[i]);
    #pragma unroll
    for (int off = 32; off >= 1; off >>= 1) m = fmaxf(m, __shfl_xor(m, off, 64));
    if ((tid & 63) == 0) red[tid >> 6] = m;
    __syncthreads();
    if (tid == 0) bcast = fmaxf(fmaxf(red[0], red[1]), fmaxf(red[2], red[3]));
    __syncthreads();
    m = bcast;

    float s = 0.f;
    #pragma unroll
    for (int i = 0; i < 8; ++i) { zi[i] = expf(zi[i] - m); s += zi[i]; }
    #pragma unroll
    for (int off = 32; off >= 1; off >>= 1) s += __shfl_xor(s, off, 64);
    __syncthreads();
    if ((tid & 63) == 0) red[tid >> 6] = s;
    __syncthreads();
    if (tid == 0) bcast = 1.f / (red[0] + red[1] + red[2] + red[3]);
    __syncthreads();
    float inv = bcast;

    #pragma unroll
    for (int i = 0; i < 8; ++i) row[tid + i * 256] = zi[i] * inv;
}

// K3: att_aggr[b][f] += sum_s X[b][s][f] * w[b][s], 4 s-chunks per batch.
__global__ __launch_bounds__(512)
void pool_kernel(const float* __restrict__ X, const float* __restrict__ w,
                 float* __restrict__ out) {
    __shared__ float wl[512];
    const int b  = blockIdx.y;
    const int sc = blockIdx.x;       // 0..3
    const int f  = threadIdx.x;      // 0..511
    const int s0 = sc * 512;
    wl[f] = w[(size_t)b * SEQ + s0 + f];
    __syncthreads();
    const float* xp = X + ((size_t)b * SEQ + s0) * DMODEL + f;
    float acc = 0.f;
    #pragma unroll 8
    for (int s = 0; s < 512; ++s)
        acc = fmaf(xp[(size_t)s * DMODEL], wl[s], acc);
    atomicAdd(&out[b * DMODEL + f], acc);
}

extern "C" void kernel_launch(void* const* d_in, const int* in_sizes, int n_in,
                              void* d_out, int out_size, void* d_ws, size_t ws_size,
                              hipStream_t stream) {
    const float* X  = (const float*)d_in[0];
    const float* Wa = (const float*)d_in[1];
    const float* ba = (const float*)d_in[2];
    const float* ae = (const float*)d_in[3];
    float* out  = (float*)d_out;
    float* feat = out;                       // [64][512]
    float* wgt  = out + BATCH * DMODEL;      // [64][2048]; holds z pre-softmax

    ushort* wa_cvt = (ushort*)d_ws;          // 640 KB of scratch

    wa_convert_kernel<<<ATT * DMODEL / 256, 256, 0, stream>>>(Wa, wa_cvt);
    scores_mfma_kernel<<<M_TOTAL / MT, 256, 0, stream>>>(X, wa_cvt, ba, ae, wgt);
    softmax_kernel<<<BATCH, 256, 0, stream>>>(wgt);
    hipMemsetAsync(feat, 0, BATCH * DMODEL * sizeof(float), stream);
    pool_kernel<<<dim3(4, BATCH), 512, 0, stream>>>(X, wgt, feat);
}

// Round 3
// 158.174 us; speedup vs baseline: 3.7255x; 1.0531x over previous
//
#include <hip/hip_runtime.h>
#include <hip/hip_bf16.h>
#include <math.h>

#define BATCH  64
#define SEQ    2048
#define DMODEL 512
#define ATT    256
#define M_TOTAL (BATCH * SEQ)

#define MT     256                      // rows per block (scores GEMM)
#define KC     32                       // k per chunk
#define NCHUNK 16
#define CHUNK_USH (ATT * KC)            // 8192 ushorts = 16 KB per chunk image
#define WA_LO_OFF (NCHUNK * CHUNK_USH)  // 131072

typedef __attribute__((ext_vector_type(8))) short short8v;
typedef __attribute__((ext_vector_type(4))) float floatx4;

__device__ __forceinline__ ushort f2bf_rne(float f) {
    unsigned u = __float_as_uint(f);
    u += 0x7FFFu + ((u >> 16) & 1u);
    return (ushort)(u >> 16);
}
__device__ __forceinline__ float bf2f(ushort h) {
    return __uint_as_float(((unsigned)h) << 16);
}
__device__ __forceinline__ void gll16(const void* g, void* l) {
    __builtin_amdgcn_global_load_lds(
        (const __attribute__((address_space(1))) unsigned*)g,
        (__attribute__((address_space(3))) unsigned*)l, 16, 0, 0);
}
// sign-free fast tanh: 1 - 2/(e^{2x}+1); exact at +-inf, 0
__device__ __forceinline__ float fast_tanh(float x) {
    return 1.0f - 2.0f * __builtin_amdgcn_rcpf(__expf(x + x) + 1.0f);
}

// XOR quad swizzle: row-major [rows][32] ushort tile, 4 quads of 8 ushorts per
// row; physical quad = logical quad ^ ((row>>2)&3). Applied identically to the
// prebuilt Wa image (linear gll16 copy), the A ds_writes, and all frag reads.

// K0: Wa fp32 [256][512] -> bf16 hi/lo per-chunk swizzled LDS images.
__global__ __launch_bounds__(256)
void wa_convert_kernel(const float* __restrict__ Wa, ushort* __restrict__ out) {
    int idx = blockIdx.x * 256 + threadIdx.x;   // 131072
    float x = Wa[idx];
    ushort hi = f2bf_rne(x);
    ushort lo = f2bf_rne(x - bf2f(hi));
    int a = idx >> 9, k = idx & 511;
    int kc = k >> 5, kk = k & 31;
    int phys = a * 32 + ((((kk >> 3) ^ ((a >> 2) & 3))) << 3) + (kk & 7);
    size_t o = (size_t)kc * CHUNK_USH + phys;
    out[o] = hi;
    out[WA_LO_OFF + o] = lo;
}

// K1: z[m] = sum_a tanh(X[m]·Wa[a] + ba[a]) * ae[a], split-bf16 3-term MFMA.
// 512 thr / 8 waves; wave (wm=wid>>1, wn=wid&1): rows [wm*64,+64), cols [wn*128,+128).
__global__ __launch_bounds__(512, 2)
void scores_mfma_kernel(const float* __restrict__ X,
                        const ushort* __restrict__ wa_cvt,
                        const float* __restrict__ ba,
                        const float* __restrict__ ae,
                        float* __restrict__ z) {
    __shared__ ushort pool[4 * CHUNK_USH];      // 64 KiB exactly
    ushort* a_hi = pool;
    ushort* a_lo = pool + CHUNK_USH;
    ushort* b_hi = pool + 2 * CHUNK_USH;
    ushort* b_lo = pool + 3 * CHUNK_USH;

    const int tid = threadIdx.x;
    const int l   = tid & 63;
    const int wid = tid >> 6;
    const int wm  = wid >> 1, wn = wid & 1;
    const int n   = l & 15,   g  = l >> 4;
    const int m0  = blockIdx.x * MT;

    // A staging: slot i handles row r_s+64i, cols [c4*4, c4*4+4)
    const int r_s = tid >> 3;
    const int c4  = tid & 7;
    const float* xbase = X + (size_t)m0 * DMODEL + c4 * 4;
    const int aw0 = r_s * 32 + ((((c4 >> 1) ^ ((r_s >> 2) & 3))) << 3) + (c4 & 1) * 4;

    // fragment read offsets (ushort units); (row>>2)&3 == (n>>2) for both
    int aoff[4], boff[8];
    const int qsw = (g ^ (n >> 2)) << 3;
    #pragma unroll
    for (int mi = 0; mi < 4; ++mi)
        aoff[mi] = (wm * 64 + mi * 16 + n) * 32 + qsw;
    #pragma unroll
    for (int nj = 0; nj < 8; ++nj)
        boff[nj] = (wn * 128 + nj * 16 + n) * 32 + qsw;

    floatx4 acc[4][8];
    #pragma unroll
    for (int i = 0; i < 4; ++i)
        #pragma unroll
        for (int j = 0; j < 8; ++j)
            acc[i][j] = (floatx4){0.f, 0.f, 0.f, 0.f};

    float4 xa[4];
    #pragma unroll
    for (int i = 0; i < 4; ++i)
        xa[i] = *(const float4*)(xbase + (size_t)(r_s + 64 * i) * DMODEL);

    #pragma unroll 1
    for (int kc = 0; kc < NCHUNK; ++kc) {
        // top barrier: prior chunk's frag reads done; X prefetch stays in flight
        asm volatile("s_waitcnt lgkmcnt(0)" ::: "memory");
        __builtin_amdgcn_s_barrier();

        // stage B chunk (4 gll16/thread, linear copy of swizzled image)
        const char* ghi = (const char*)(wa_cvt + (size_t)kc * CHUNK_USH);
        const char* glo = (const char*)(wa_cvt + WA_LO_OFF + (size_t)kc * CHUNK_USH);
        #pragma unroll
        for (int i = 0; i < 2; ++i) {
            int seg = wid * 2 + i;                  // 16 segs x 1024 B per half
            gll16(ghi + seg * 1024 + l * 16, (char*)b_hi + seg * 1024);
            gll16(glo + seg * 1024 + l * 16, (char*)b_lo + seg * 1024);
        }
        // stage A: split prefetched X regs into hi/lo, swizzled ds_write_b64
        #pragma unroll
        for (int i = 0; i < 4; ++i) {
            ushort4 h, lo;
            h.x = f2bf_rne(xa[i].x); lo.x = f2bf_rne(xa[i].x - bf2f(h.x));
            h.y = f2bf_rne(xa[i].y); lo.y = f2bf_rne(xa[i].y - bf2f(h.y));
            h.z = f2bf_rne(xa[i].z); lo.z = f2bf_rne(xa[i].z - bf2f(h.z));
            h.w = f2bf_rne(xa[i].w); lo.w = f2bf_rne(xa[i].w - bf2f(h.w));
            *(ushort4*)&a_hi[aw0 + i * 2048] = h;
            *(ushort4*)&a_lo[aw0 + i * 2048] = lo;
        }
        if (kc + 1 < NCHUNK) {
            // fence pins VMEM issue order: gll16 (4) then X loads (4)
            asm volatile("" ::: "memory");
            #pragma unroll
            for (int i = 0; i < 4; ++i)
                xa[i] = *(const float4*)(xbase + (size_t)(r_s + 64 * i) * DMODEL
                                         + (kc + 1) * KC);
            // drain gll16 (leave the 4 newest = X prefetch in flight) + ds_writes
            asm volatile("s_waitcnt vmcnt(4) lgkmcnt(0)" ::: "memory");
        } else {
            asm volatile("s_waitcnt vmcnt(0) lgkmcnt(0)" ::: "memory");
        }
        __builtin_amdgcn_s_barrier();

        // compute: 96 MFMAs per wave per chunk
        short8v ah[4], av[4];
        #pragma unroll
        for (int mi = 0; mi < 4; ++mi) {
            ah[mi] = *(const short8v*)&a_hi[aoff[mi]];
            av[mi] = *(const short8v*)&a_lo[aoff[mi]];
        }
        #pragma unroll
        for (int nj = 0; nj < 8; ++nj) {
            short8v bh = *(const short8v*)&b_hi[boff[nj]];
            short8v bv = *(const short8v*)&b_lo[boff[nj]];
            #pragma unroll
            for (int mi = 0; mi < 4; ++mi) {
                acc[mi][nj] = __builtin_amdgcn_mfma_f32_16x16x32_bf16(av[mi], bh, acc[mi][nj], 0, 0, 0);
                acc[mi][nj] = __builtin_amdgcn_mfma_f32_16x16x32_bf16(ah[mi], bv, acc[mi][nj], 0, 0, 0);
                acc[mi][nj] = __builtin_amdgcn_mfma_f32_16x16x32_bf16(ah[mi], bh, acc[mi][nj], 0, 0, 0);
            }
        }
    }

    __syncthreads();                     // all compute done; pool reusable
    float* zb = (float*)pool;            // [2][256] partial z

    float bav[8], aev[8];
    #pragma unroll
    for (int nj = 0; nj < 8; ++nj) {
        int c = wn * 128 + nj * 16 + n;
        bav[nj] = ba[c];
        aev[nj] = ae[c];
    }
    // C/D map (HW-verified r2): M-row = wm*64 + mi*16 + g*4 + e, col = ... + n
    #pragma unroll
    for (int mi = 0; mi < 4; ++mi) {
        float zp[4] = {0.f, 0.f, 0.f, 0.f};
        #pragma unroll
        for (int nj = 0; nj < 8; ++nj)
            #pragma unroll
            for (int e = 0; e < 4; ++e)
                zp[e] += fast_tanh(acc[mi][nj][e] + bav[nj]) * aev[nj];
        #pragma unroll
        for (int off = 8; off >= 1; off >>= 1)
            #pragma unroll
            for (int e = 0; e < 4; ++e)
                zp[e] += __shfl_xor(zp[e], off, 64);
        if (n == 0)
            *(float4*)&zb[wn * 256 + wm * 64 + mi * 16 + g * 4] =
                make_float4(zp[0], zp[1], zp[2], zp[3]);
    }
    __syncthreads();
    if (tid < MT)
        z[m0 + tid] = zb[tid] + zb[256 + tid];
}

// K2: in-place softmax over SEQ per batch.
__global__ __launch_bounds__(256)
void softmax_kernel(float* __restrict__ zw) {
    __shared__ float red[4];
    __shared__ float bcast;
    const int b = blockIdx.x, tid = threadIdx.x;
    float* row = zw + (size_t)b * SEQ;

    float zi[8];
    #pragma unroll
    for (int i = 0; i < 8; ++i) zi[i] = row[tid + i * 256];

    float m = -3.0e38f;
    #pragma unroll
    for (int i = 0; i < 8; ++i) m = fmaxf(m, zi[i]);
    #pragma unroll
    for (int off = 32; off >= 1; off >>= 1) m = fmaxf(m, __shfl_xor(m, off, 64));
    if ((tid & 63) == 0) red[tid >> 6] = m;
    __syncthreads();
    if (tid == 0) bcast = fmaxf(fmaxf(red[0], red[1]), fmaxf(red[2], red[3]));
    __syncthreads();
    m = bcast;

    float s = 0.f;
    #pragma unroll
    for (int i = 0; i < 8; ++i) { zi[i] = expf(zi[i] - m); s += zi[i]; }
    #pragma unroll
    for (int off = 32; off >= 1; off >>= 1) s += __shfl_xor(s, off, 64);
    __syncthreads();
    if ((tid & 63) == 0) red[tid >> 6] = s;
    __syncthreads();
    if (tid == 0) bcast = 1.f / (red[0] + red[1] + red[2] + red[3]);
    __syncthreads();
    float inv = bcast;

    #pragma unroll
    for (int i = 0; i < 8; ++i) row[tid + i * 256] = zi[i] * inv;
}

// K3: att_aggr[b][f] += sum_s X[b][s][f] * w[b][s], 4 s-chunks per batch.
__global__ __launch_bounds__(512)
void pool_kernel(const float* __restrict__ X, const float* __restrict__ w,
                 float* __restrict__ out) {
    __shared__ float wl[512];
    const int b  = blockIdx.y;
    const int sc = blockIdx.x;
    const int f  = threadIdx.x;
    const int s0 = sc * 512;
    wl[f] = w[(size_t)b * SEQ + s0 + f];
    __syncthreads();
    const float* xp = X + ((size_t)b * SEQ + s0) * DMODEL + f;
    float acc = 0.f;
    #pragma unroll 8
    for (int s = 0; s < 512; ++s)
        acc = fmaf(xp[(size_t)s * DMODEL], wl[s], acc);
    atomicAdd(&out[b * DMODEL + f], acc);
}

extern "C" void kernel_launch(void* const* d_in, const int* in_sizes, int n_in,
                              void* d_out, int out_size, void* d_ws, size_t ws_size,
                              hipStream_t stream) {
    const float* X  = (const float*)d_in[0];
    const float* Wa = (const float*)d_in[1];
    const float* ba = (const float*)d_in[2];
    const float* ae = (const float*)d_in[3];
    float* out  = (float*)d_out;
    float* feat = out;                       // [64][512]
    float* wgt  = out + BATCH * DMODEL;      // [64][2048]; z pre-softmax

    ushort* wa_cvt = (ushort*)d_ws;          // 512 KB scratch

    wa_convert_kernel<<<ATT * DMODEL / 256, 256, 0, stream>>>(Wa, wa_cvt);
    scores_mfma_kernel<<<M_TOTAL / MT, 512, 0, stream>>>(X, wa_cvt, ba, ae, wgt);
    softmax_kernel<<<BATCH, 256, 0, stream>>>(wgt);
    hipMemsetAsync(feat, 0, BATCH * DMODEL * sizeof(float), stream);
    pool_kernel<<<dim3(4, BATCH), 512, 0, stream>>>(X, wgt, feat);
}

// Round 4
// 145.695 us; speedup vs baseline: 4.0446x; 1.0857x over previous
//
#include <hip/hip_runtime.h>
#include <hip/hip_bf16.h>
#include <math.h>

#define BATCH  64
#define SEQ    2048
#define DMODEL 512
#define ATT    256
#define M_TOTAL (BATCH * SEQ)

#define MT     256                      // rows per block (scores GEMM)
#define KC     32                       // k per chunk
#define NCHUNK 16
#define CHUNK_USH (ATT * KC)            // 8192 ushorts = 16 KB per tile
#define WA_LO_OFF (NCHUNK * CHUNK_USH)  // 131072 ushorts

typedef __attribute__((ext_vector_type(8))) short short8v;
typedef __attribute__((ext_vector_type(4))) float floatx4;

__device__ __forceinline__ ushort f2bf_rne(float f) {
    unsigned u = __float_as_uint(f);
    u += 0x7FFFu + ((u >> 16) & 1u);
    return (ushort)(u >> 16);
}
__device__ __forceinline__ float bf2f(ushort h) {
    return __uint_as_float(((unsigned)h) << 16);
}
__device__ __forceinline__ void gll16(const void* g, void* l) {
    __builtin_amdgcn_global_load_lds(
        (const __attribute__((address_space(1))) unsigned*)g,
        (__attribute__((address_space(3))) unsigned*)l, 16, 0, 0);
}
// sign-free fast tanh: 1 - 2/(e^{2x}+1); exact at +-inf, 0
__device__ __forceinline__ float fast_tanh(float x) {
    return 1.0f - 2.0f * __builtin_amdgcn_rcpf(__expf(x + x) + 1.0f);
}

// Split 8 floats (one k-quad... 2 quads of 4) into packed bf16 hi (truncation)
// and bf16 lo (RNE of remainder). hw word p = [bf(f[2p+1]) : bf(f[2p])].
__device__ __forceinline__ void cvt_quad(float4 a, float4 b, uint4& hi, uint4& lo) {
    float f[8] = {a.x, a.y, a.z, a.w, b.x, b.y, b.z, b.w};
    unsigned hw[4], lw[4];
    #pragma unroll
    for (int p = 0; p < 4; ++p) {
        unsigned u0 = __float_as_uint(f[2 * p]);
        unsigned u1 = __float_as_uint(f[2 * p + 1]);
        hw[p] = __builtin_amdgcn_perm(u1, u0, 0x07060302u);  // [u1.hi16, u0.hi16]
        float r0 = f[2 * p]     - __uint_as_float(u0 & 0xFFFF0000u);
        float r1 = f[2 * p + 1] - __uint_as_float(u1 & 0xFFFF0000u);
        unsigned pk;
        asm("v_cvt_pk_bf16_f32 %0, %1, %2" : "=v"(pk) : "v"(r0), "v"(r1));
        lw[p] = pk;
    }
    hi = make_uint4(hw[0], hw[1], hw[2], hw[3]);
    lo = make_uint4(lw[0], lw[1], lw[2], lw[3]);
}

// K0: Wa fp32 [256][512] -> bf16 hi/lo per-chunk quad-major LDS images:
// elem (a, k): chunk kc=k>>5, quad q=(k&31)>>3 -> offset kc*8192 + (q*256+a)*8 + (k&7)
__global__ __launch_bounds__(256)
void wa_convert_kernel(const float* __restrict__ Wa, ushort* __restrict__ out) {
    int idx = blockIdx.x * 256 + threadIdx.x;   // 131072
    float x = Wa[idx];
    ushort hi = f2bf_rne(x);
    ushort lo = f2bf_rne(x - bf2f(hi));
    int a = idx >> 9, k = idx & 511;
    int kc = k >> 5, kk = k & 31, q = kk >> 3;
    size_t o = (size_t)kc * CHUNK_USH + (size_t)(q * 256 + a) * 8 + (kk & 7);
    out[o] = hi;
    out[WA_LO_OFF + o] = lo;
}

__device__ __forceinline__ void stage_chunk(ushort* nb, int chunk, const float4* xa,
                                            const ushort* __restrict__ wa_cvt,
                                            int r_a, int h_a, int wid, int l) {
    ushort* ah = nb;
    ushort* al = nb + CHUNK_USH;
    ushort* bh = nb + 2 * CHUNK_USH;
    ushort* bl = nb + 3 * CHUNK_USH;
    uint4 h0, l0, h1, l1;
    cvt_quad(xa[0], xa[1], h0, l0);
    cvt_quad(xa[2], xa[3], h1, l1);
    const int q0 = 2 * h_a, q1 = q0 + 1;
    *(uint4*)&ah[(size_t)(q0 * 256 + r_a) * 8] = h0;
    *(uint4*)&al[(size_t)(q0 * 256 + r_a) * 8] = l0;
    *(uint4*)&ah[(size_t)(q1 * 256 + r_a) * 8] = h1;
    *(uint4*)&al[(size_t)(q1 * 256 + r_a) * 8] = l1;
    const char* ghi = (const char*)(wa_cvt + (size_t)chunk * CHUNK_USH);
    const char* glo = (const char*)(wa_cvt + (size_t)WA_LO_OFF + (size_t)chunk * CHUNK_USH);
    #pragma unroll
    for (int i = 0; i < 2; ++i) {
        int seg = wid * 2 + i;                  // 16 segs x 1 KB per tile
        gll16(ghi + seg * 1024 + l * 16, (char*)bh + seg * 1024);
        gll16(glo + seg * 1024 + l * 16, (char*)bl + seg * 1024);
    }
}

// K1: z[m] = sum_a tanh(X[m]·Wa[a] + ba[a]) * ae[a], split-bf16 3-term MFMA.
// 512 thr / 8 waves, tile 256x256, double-buffered LDS, 1 barrier per chunk.
__global__ __launch_bounds__(512, 2)
void scores_mfma_kernel(const float* __restrict__ X,
                        const ushort* __restrict__ wa_cvt,
                        const float* __restrict__ ba,
                        const float* __restrict__ ae,
                        float* __restrict__ z) {
    __shared__ __align__(16) ushort pool[8 * CHUNK_USH];   // 128 KiB

    const int tid = threadIdx.x;
    const int l   = tid & 63;
    const int wid = tid >> 6;
    const int wm  = wid >> 1, wn = wid & 1;
    const int n   = l & 15,   g  = l >> 4;
    const int m0  = blockIdx.x * MT;
    const int r_a = tid & 255;      // staged row
    const int h_a = tid >> 8;       // staged k-half (quads 2h, 2h+1)

    // thread's X source: 16 floats per chunk at float4s [kc*8 + h*4 .. +4)
    const float4* xq = (const float4*)(X + (size_t)(m0 + r_a) * DMODEL) + h_a * 4;

    // frag offsets in quad-major tile: (g*256 + row)*8 ushorts
    int aoff[4], boff[8];
    #pragma unroll
    for (int mi = 0; mi < 4; ++mi) aoff[mi] = g * 2048 + (wm * 64 + mi * 16 + n) * 8;
    #pragma unroll
    for (int nj = 0; nj < 8; ++nj) boff[nj] = g * 2048 + (wn * 128 + nj * 16 + n) * 8;

    floatx4 acc[4][8];
    #pragma unroll
    for (int i = 0; i < 4; ++i)
        #pragma unroll
        for (int j = 0; j < 8; ++j)
            acc[i][j] = (floatx4){0.f, 0.f, 0.f, 0.f};

    float4 xa[4];
    #pragma unroll
    for (int i = 0; i < 4; ++i) xa[i] = xq[i];              // chunk 0
    stage_chunk(pool, 0, xa, wa_cvt, r_a, h_a, wid, l);
    asm volatile("" ::: "memory");                          // keep X loads after glls
    #pragma unroll
    for (int i = 0; i < 4; ++i) xa[i] = xq[8 + i];          // chunk 1
    asm volatile("s_waitcnt vmcnt(4) lgkmcnt(0)" ::: "memory");
    __builtin_amdgcn_s_barrier();

    #pragma unroll 1
    for (int kc = 0; kc < NCHUNK; ++kc) {
        ushort* cb = pool + (kc & 1) * (4 * CHUNK_USH);
        if (kc + 1 < NCHUNK) {
            ushort* nb = pool + ((kc + 1) & 1) * (4 * CHUNK_USH);
            stage_chunk(nb, kc + 1, xa, wa_cvt, r_a, h_a, wid, l);
            if (kc + 2 < NCHUNK) {
                asm volatile("" ::: "memory");              // gll before X in vmcnt order
                #pragma unroll
                for (int i = 0; i < 4; ++i) xa[i] = xq[(kc + 2) * 8 + i];
            }
        }
        const ushort* ah_t = cb;
        const ushort* al_t = cb + CHUNK_USH;
        const ushort* bh_t = cb + 2 * CHUNK_USH;
        const ushort* bl_t = cb + 3 * CHUNK_USH;

        short8v ah[4], av[4];
        #pragma unroll
        for (int mi = 0; mi < 4; ++mi) {
            ah[mi] = *(const short8v*)&ah_t[aoff[mi]];
            av[mi] = *(const short8v*)&al_t[aoff[mi]];
        }
        #pragma unroll
        for (int nj = 0; nj < 8; ++nj) {
            short8v bh = *(const short8v*)&bh_t[boff[nj]];
            short8v bv = *(const short8v*)&bl_t[boff[nj]];
            #pragma unroll
            for (int mi = 0; mi < 4; ++mi) {
                acc[mi][nj] = __builtin_amdgcn_mfma_f32_16x16x32_bf16(av[mi], bh, acc[mi][nj], 0, 0, 0);
                acc[mi][nj] = __builtin_amdgcn_mfma_f32_16x16x32_bf16(ah[mi], bv, acc[mi][nj], 0, 0, 0);
                acc[mi][nj] = __builtin_amdgcn_mfma_f32_16x16x32_bf16(ah[mi], bh, acc[mi][nj], 0, 0, 0);
            }
        }
        if (kc + 1 < NCHUNK) {
            if (kc + 2 < NCHUNK)
                asm volatile("s_waitcnt vmcnt(4) lgkmcnt(0)" ::: "memory");
            else
                asm volatile("s_waitcnt vmcnt(0) lgkmcnt(0)" ::: "memory");
            __builtin_amdgcn_s_barrier();
        }
    }

    __syncthreads();                     // all compute done; pool reusable
    float* zb = (float*)pool;            // [2][256] partial z

    float bav[8], aev[8];
    #pragma unroll
    for (int nj = 0; nj < 8; ++nj) {
        int c = wn * 128 + nj * 16 + n;
        bav[nj] = ba[c];
        aev[nj] = ae[c];
    }
    // C/D map (HW-verified): M-row = wm*64 + mi*16 + g*4 + e, col = wn*128 + nj*16 + n
    #pragma unroll
    for (int mi = 0; mi < 4; ++mi) {
        float zp[4] = {0.f, 0.f, 0.f, 0.f};
        #pragma unroll
        for (int nj = 0; nj < 8; ++nj)
            #pragma unroll
            for (int e = 0; e < 4; ++e)
                zp[e] += fast_tanh(acc[mi][nj][e] + bav[nj]) * aev[nj];
        #pragma unroll
        for (int off = 8; off >= 1; off >>= 1)
            #pragma unroll
            for (int e = 0; e < 4; ++e)
                zp[e] += __shfl_xor(zp[e], off, 64);
        if (n == 0)
            *(float4*)&zb[wn * 256 + wm * 64 + mi * 16 + g * 4] =
                make_float4(zp[0], zp[1], zp[2], zp[3]);
    }
    __syncthreads();
    if (tid < MT)
        z[m0 + tid] = zb[tid] + zb[256 + tid];
}

// K2: in-place softmax over SEQ per batch.
__global__ __launch_bounds__(256)
void softmax_kernel(float* __restrict__ zw) {
    __shared__ float red[4];
    __shared__ float bcast;
    const int b = blockIdx.x, tid = threadIdx.x;
    float* row = zw + (size_t)b * SEQ;

    float zi[8];
    #pragma unroll
    for (int i = 0; i < 8; ++i) zi[i] = row[tid + i * 256];

    float m = -3.0e38f;
    #pragma unroll
    for (int i = 0; i < 8; ++i) m = fmaxf(m, zi[i]);
    #pragma unroll
    for (int off = 32; off >= 1; off >>= 1) m = fmaxf(m, __shfl_xor(m, off, 64));
    if ((tid & 63) == 0) red[tid >> 6] = m;
    __syncthreads();
    if (tid == 0) bcast = fmaxf(fmaxf(red[0], red[1]), fmaxf(red[2], red[3]));
    __syncthreads();
    m = bcast;

    float s = 0.f;
    #pragma unroll
    for (int i = 0; i < 8; ++i) { zi[i] = expf(zi[i] - m); s += zi[i]; }
    #pragma unroll
    for (int off = 32; off >= 1; off >>= 1) s += __shfl_xor(s, off, 64);
    __syncthreads();
    if ((tid & 63) == 0) red[tid >> 6] = s;
    __syncthreads();
    if (tid == 0) bcast = 1.f / (red[0] + red[1] + red[2] + red[3]);
    __syncthreads();
    float inv = bcast;

    #pragma unroll
    for (int i = 0; i < 8; ++i) row[tid + i * 256] = zi[i] * inv;
}

// K3: att_aggr[b][f] += sum_s X[b][s][f] * w[b][s], 8 s-chunks x 256 per batch.
#define PCHUNK 256
__global__ __launch_bounds__(512)
void pool_kernel(const float* __restrict__ X, const float* __restrict__ w,
                 float* __restrict__ out) {
    __shared__ float wl[PCHUNK];
    const int b  = blockIdx.y;
    const int sc = blockIdx.x;       // 0..7
    const int f  = threadIdx.x;      // 0..511
    const int s0 = sc * PCHUNK;
    if (f < PCHUNK) wl[f] = w[(size_t)b * SEQ + s0 + f];
    __syncthreads();
    const float* xp = X + ((size_t)b * SEQ + s0) * DMODEL + f;
    float a0 = 0.f, a1 = 0.f, a2 = 0.f, a3 = 0.f;
    #pragma unroll 4
    for (int s = 0; s < PCHUNK; s += 4) {
        a0 = fmaf(xp[(size_t)(s + 0) * DMODEL], wl[s + 0], a0);
        a1 = fmaf(xp[(size_t)(s + 1) * DMODEL], wl[s + 1], a1);
        a2 = fmaf(xp[(size_t)(s + 2) * DMODEL], wl[s + 2], a2);
        a3 = fmaf(xp[(size_t)(s + 3) * DMODEL], wl[s + 3], a3);
    }
    atomicAdd(&out[b * DMODEL + f], (a0 + a1) + (a2 + a3));
}

extern "C" void kernel_launch(void* const* d_in, const int* in_sizes, int n_in,
                              void* d_out, int out_size, void* d_ws, size_t ws_size,
                              hipStream_t stream) {
    const float* X  = (const float*)d_in[0];
    const float* Wa = (const float*)d_in[1];
    const float* ba = (const float*)d_in[2];
    const float* ae = (const float*)d_in[3];
    float* out  = (float*)d_out;
    float* feat = out;                       // [64][512]
    float* wgt  = out + BATCH * DMODEL;      // [64][2048]; z pre-softmax

    ushort* wa_cvt = (ushort*)d_ws;          // 512 KB scratch

    wa_convert_kernel<<<ATT * DMODEL / 256, 256, 0, stream>>>(Wa, wa_cvt);
    scores_mfma_kernel<<<M_TOTAL / MT, 512, 0, stream>>>(X, wa_cvt, ba, ae, wgt);
    softmax_kernel<<<BATCH, 256, 0, stream>>>(wgt);
    hipMemsetAsync(feat, 0, BATCH * DMODEL * sizeof(float), stream);
    pool_kernel<<<dim3(SEQ / PCHUNK, BATCH), 512, 0, stream>>>(X, wgt, feat);
}

// Round 6
// 145.610 us; speedup vs baseline: 4.0469x; 1.0006x over previous
//
#include <hip/hip_runtime.h>
#include <hip/hip_bf16.h>
#include <math.h>

#define BATCH  64
#define SEQ    2048
#define DMODEL 512
#define ATT    256
#define M_TOTAL (BATCH * SEQ)

#define MT     256                      // rows per block (scores GEMM)
#define KC     32                       // k per chunk
#define NCHUNK 16
#define CHUNK_USH (ATT * KC)            // 8192 ushorts = 16 KB per tile
#define WA_LO_OFF (NCHUNK * CHUNK_USH)  // 131072 ushorts

// d_ws layout
#define XH_OFF    (1u << 20)                          // 1 MB (wa_cvt lives below)
#define XH_BYTES  ((size_t)M_TOTAL * DMODEL * 2)      // 128 MB bf16 X-hi
#define PART_OFF  (XH_OFF + XH_BYTES)
#define PART_BYTES ((size_t)8 * BATCH * DMODEL * 4)   // 1 MB
#define WS_NEED   (PART_OFF + PART_BYTES)

typedef __attribute__((ext_vector_type(8))) short short8v;
typedef __attribute__((ext_vector_type(4))) float floatx4;

__device__ __forceinline__ ushort f2bf_rne(float f) {
    unsigned u = __float_as_uint(f);
    u += 0x7FFFu + ((u >> 16) & 1u);
    return (ushort)(u >> 16);
}
__device__ __forceinline__ float bf2f(ushort h) {
    return __uint_as_float(((unsigned)h) << 16);
}
__device__ __forceinline__ void gll16(const void* g, void* l) {
    __builtin_amdgcn_global_load_lds(
        (const __attribute__((address_space(1))) unsigned*)g,
        (__attribute__((address_space(3))) unsigned*)l, 16, 0, 0);
}
// sign-free fast tanh: 1 - 2/(e^{2x}+1); exact at +-inf, 0
__device__ __forceinline__ float fast_tanh(float x) {
    return 1.0f - 2.0f * __builtin_amdgcn_rcpf(__expf(x + x) + 1.0f);
}
// float4 -> packed bf16 hi (truncation) + lo (RNE of remainder)
__device__ __forceinline__ void cvt4(float4 v, uint2& hi, uint2& lo) {
    unsigned u0 = __float_as_uint(v.x), u1 = __float_as_uint(v.y);
    unsigned u2 = __float_as_uint(v.z), u3 = __float_as_uint(v.w);
    hi.x = __builtin_amdgcn_perm(u1, u0, 0x07060302u);   // [bf(y):bf(x)]
    hi.y = __builtin_amdgcn_perm(u3, u2, 0x07060302u);
    float r0 = v.x - __uint_as_float(u0 & 0xFFFF0000u);
    float r1 = v.y - __uint_as_float(u1 & 0xFFFF0000u);
    float r2 = v.z - __uint_as_float(u2 & 0xFFFF0000u);
    float r3 = v.w - __uint_as_float(u3 & 0xFFFF0000u);
    asm("v_cvt_pk_bf16_f32 %0, %1, %2" : "=v"(lo.x) : "v"(r0), "v"(r1));
    asm("v_cvt_pk_bf16_f32 %0, %1, %2" : "=v"(lo.y) : "v"(r2), "v"(r3));
}

// K0: Wa fp32 [256][512] -> bf16 hi/lo per-chunk quad-major LDS images:
// elem (a, k): chunk kc=k>>5, quad q=(k&31)>>3 -> kc*8192 + (q*256+a)*8 + (k&7)
__global__ __launch_bounds__(256)
void wa_convert_kernel(const float* __restrict__ Wa, ushort* __restrict__ out) {
    int idx = blockIdx.x * 256 + threadIdx.x;   // 131072
    float x = Wa[idx];
    ushort hi = f2bf_rne(x);
    ushort lo = f2bf_rne(x - bf2f(hi));
    int a = idx >> 9, k = idx & 511;
    int kc = k >> 5, kk = k & 31, q = kk >> 3;
    size_t o = (size_t)kc * CHUNK_USH + (size_t)(q * 256 + a) * 8 + (kk & 7);
    out[o] = hi;
    out[WA_LO_OFF + o] = lo;
}

// stage one K-chunk: convert prefetched X regs -> LDS (+X_hi global), gll B.
// thread t: rows sr+64i (sr=t>>3), cols [sc*4, sc*4+4) (sc=t&7) within chunk.
// xh_base = Xh + m0*DMODEL (row offset r applied HERE, exactly once).
__device__ __forceinline__ void stage_chunk(ushort* nb, int chunk, const float4* xa,
                                            const ushort* __restrict__ wa_cvt,
                                            ushort* xh_base, int sr, int sc,
                                            int wid, int l) {
    ushort* ah = nb;
    ushort* al = nb + CHUNK_USH;
    ushort* bh = nb + 2 * CHUNK_USH;
    ushort* bl = nb + 3 * CHUNK_USH;
    const int q = sc >> 1, h = (sc & 1) * 4;
    #pragma unroll
    for (int i = 0; i < 4; ++i) {
        uint2 hi, lo;
        cvt4(xa[i], hi, lo);
        int r = sr + 64 * i;
        *(uint2*)&ah[(q * 256 + r) * 8 + h] = hi;
        *(uint2*)&al[(q * 256 + r) * 8 + h] = lo;
        if (xh_base)
            *(uint2*)&xh_base[(size_t)r * DMODEL + chunk * KC + sc * 4] = hi;
    }
    const char* ghi = (const char*)(wa_cvt + (size_t)chunk * CHUNK_USH);
    const char* glo = (const char*)(wa_cvt + (size_t)WA_LO_OFF + (size_t)chunk * CHUNK_USH);
    #pragma unroll
    for (int i = 0; i < 2; ++i) {
        int seg = wid * 2 + i;                  // 16 segs x 1 KB per tile
        gll16(ghi + seg * 1024 + l * 16, (char*)bh + seg * 1024);
        gll16(glo + seg * 1024 + l * 16, (char*)bl + seg * 1024);
    }
}

// K1: z[m] = sum_a tanh(X[m]·Wa[a] + ba[a]) * ae[a], split-bf16 3-term MFMA.
// 512 thr / 8 waves, tile 256x256, double-buffered LDS, 1 barrier per chunk.
__global__ __launch_bounds__(512, 2)
void scores_mfma_kernel(const float* __restrict__ X,
                        const ushort* __restrict__ wa_cvt,
                        const float* __restrict__ ba,
                        const float* __restrict__ ae,
                        float* __restrict__ z,
                        ushort* __restrict__ Xh) {
    __shared__ __align__(16) ushort pool[8 * CHUNK_USH];   // 128 KiB

    const int tid = threadIdx.x;
    const int l   = tid & 63;
    const int wid = tid >> 6;
    const int wm  = wid >> 1, wn = wid & 1;
    const int n   = l & 15,   g  = l >> 4;
    const int m0  = blockIdx.x * MT;
    const int sr  = tid >> 3;       // staging base row (0..63)
    const int sc  = tid & 7;        // staging 16B col-quad

    // coalesced X source: wave = 8 rows x 128B full lines
    const float4* xq = (const float4*)(X + (size_t)(m0 + sr) * DMODEL) + sc;
    ushort* xh_base = Xh ? (Xh + (size_t)m0 * DMODEL) : nullptr;  // r added in stage

    // frag offsets in quad-major tile: (g*256 + row)*8 ushorts
    int aoff[4], boff[8];
    #pragma unroll
    for (int mi = 0; mi < 4; ++mi) aoff[mi] = g * 2048 + (wm * 64 + mi * 16 + n) * 8;
    #pragma unroll
    for (int nj = 0; nj < 8; ++nj) boff[nj] = g * 2048 + (wn * 128 + nj * 16 + n) * 8;

    floatx4 acc[4][8];
    #pragma unroll
    for (int i = 0; i < 4; ++i)
        #pragma unroll
        for (int j = 0; j < 8; ++j)
            acc[i][j] = (floatx4){0.f, 0.f, 0.f, 0.f};

    float4 xa[4];
    #pragma unroll
    for (int i = 0; i < 4; ++i) xa[i] = xq[i * 8192];        // chunk 0
    stage_chunk(pool, 0, xa, wa_cvt, xh_base, sr, sc, wid, l);
    asm volatile("" ::: "memory");                           // stores/glls before X
    #pragma unroll
    for (int i = 0; i < 4; ++i) xa[i] = xq[8 + i * 8192];    // chunk 1
    asm volatile("s_waitcnt vmcnt(4) lgkmcnt(0)" ::: "memory");
    __builtin_amdgcn_s_barrier();

    #pragma unroll 1
    for (int kc = 0; kc < NCHUNK; ++kc) {
        ushort* cb = pool + (kc & 1) * (4 * CHUNK_USH);
        if (kc + 1 < NCHUNK) {
            ushort* nb = pool + ((kc + 1) & 1) * (4 * CHUNK_USH);
            stage_chunk(nb, kc + 1, xa, wa_cvt, xh_base, sr, sc, wid, l);
            if (kc + 2 < NCHUNK) {
                asm volatile("" ::: "memory");               // glls before X in vm order
                #pragma unroll
                for (int i = 0; i < 4; ++i)
                    xa[i] = xq[(kc + 2) * 8 + i * 8192];
            }
        }
        const ushort* ah_t = cb;
        const ushort* al_t = cb + CHUNK_USH;
        const ushort* bh_t = cb + 2 * CHUNK_USH;
        const ushort* bl_t = cb + 3 * CHUNK_USH;

        short8v ah[4], av[4];
        #pragma unroll
        for (int mi = 0; mi < 4; ++mi) {
            ah[mi] = *(const short8v*)&ah_t[aoff[mi]];
            av[mi] = *(const short8v*)&al_t[aoff[mi]];
        }
        #pragma unroll
        for (int nj = 0; nj < 8; ++nj) {
            short8v bh = *(const short8v*)&bh_t[boff[nj]];
            short8v bv = *(const short8v*)&bl_t[boff[nj]];
            #pragma unroll
            for (int mi = 0; mi < 4; ++mi) {
                acc[mi][nj] = __builtin_amdgcn_mfma_f32_16x16x32_bf16(av[mi], bh, acc[mi][nj], 0, 0, 0);
                acc[mi][nj] = __builtin_amdgcn_mfma_f32_16x16x32_bf16(ah[mi], bv, acc[mi][nj], 0, 0, 0);
                acc[mi][nj] = __builtin_amdgcn_mfma_f32_16x16x32_bf16(ah[mi], bh, acc[mi][nj], 0, 0, 0);
            }
        }
        if (kc + 1 < NCHUNK) {
            if (kc + 2 < NCHUNK)
                asm volatile("s_waitcnt vmcnt(4) lgkmcnt(0)" ::: "memory");
            else
                asm volatile("s_waitcnt vmcnt(0) lgkmcnt(0)" ::: "memory");
            __builtin_amdgcn_s_barrier();
        }
    }

    __syncthreads();                     // all compute done; pool reusable
    float* zb = (float*)pool;            // [2][256] partial z

    float bav[8], aev[8];
    #pragma unroll
    for (int nj = 0; nj < 8; ++nj) {
        int c = wn * 128 + nj * 16 + n;
        bav[nj] = ba[c];
        aev[nj] = ae[c];
    }
    // C/D map (HW-verified): M-row = wm*64 + mi*16 + g*4 + e, col = wn*128 + nj*16 + n
    #pragma unroll
    for (int mi = 0; mi < 4; ++mi) {
        float zp[4] = {0.f, 0.f, 0.f, 0.f};
        #pragma unroll
        for (int nj = 0; nj < 8; ++nj)
            #pragma unroll
            for (int e = 0; e < 4; ++e)
                zp[e] += fast_tanh(acc[mi][nj][e] + bav[nj]) * aev[nj];
        #pragma unroll
        for (int off = 8; off >= 1; off >>= 1)
            #pragma unroll
            for (int e = 0; e < 4; ++e)
                zp[e] += __shfl_xor(zp[e], off, 64);
        if (n == 0)
            *(float4*)&zb[wn * 256 + wm * 64 + mi * 16 + g * 4] =
                make_float4(zp[0], zp[1], zp[2], zp[3]);
    }
    __syncthreads();
    if (tid < MT)
        z[m0 + tid] = zb[tid] + zb[256 + tid];
}

// K2: in-place softmax over SEQ per batch.
__global__ __launch_bounds__(256)
void softmax_kernel(float* __restrict__ zw) {
    __shared__ float red[4];
    __shared__ float bcast;
    const int b = blockIdx.x, tid = threadIdx.x;
    float* row = zw + (size_t)b * SEQ;

    float zi[8];
    #pragma unroll
    for (int i = 0; i < 8; ++i) zi[i] = row[tid + i * 256];

    float m = -3.0e38f;
    #pragma unroll
    for (int i = 0; i < 8; ++i) m = fmaxf(m, zi[i]);
    #pragma unroll
    for (int off = 32; off >= 1; off >>= 1) m = fmaxf(m, __shfl_xor(m, off, 64));
    if ((tid & 63) == 0) red[tid >> 6] = m;
    __syncthreads();
    if (tid == 0) bcast = fmaxf(fmaxf(red[0], red[1]), fmaxf(red[2], red[3]));
    __syncthreads();
    m = bcast;

    float s = 0.f;
    #pragma unroll
    for (int i = 0; i < 8; ++i) { zi[i] = expf(zi[i] - m); s += zi[i]; }
    #pragma unroll
    for (int off = 32; off >= 1; off >>= 1) s += __shfl_xor(s, off, 64);
    __syncthreads();
    if ((tid & 63) == 0) red[tid >> 6] = s;
    __syncthreads();
    if (tid == 0) bcast = 1.f / (red[0] + red[1] + red[2] + red[3]);
    __syncthreads();
    float inv = bcast;

    #pragma unroll
    for (int i = 0; i < 8; ++i) row[tid + i * 256] = zi[i] * inv;
}

// K3a: bf16 pool partials: partials[sc][b][f] = sum_{s in chunk} w[s]*Xh[b,s,f]
#define PCHUNK 256
__global__ __launch_bounds__(512)
void pool_bf16_kernel(const ushort* __restrict__ Xh, const float* __restrict__ w,
                      float* __restrict__ partials) {
    __shared__ float wl[PCHUNK];
    __shared__ float2 accs[512];
    const int b  = blockIdx.y;
    const int sc = blockIdx.x;       // 0..7
    const int t  = threadIdx.x;
    const int u  = t & 255;          // uint idx: features 2u, 2u+1
    const int p  = t >> 8;           // row parity
    const int s0 = sc * PCHUNK;
    if (t < PCHUNK) wl[t] = w[(size_t)b * SEQ + s0 + t];
    __syncthreads();
    const uint* xp = (const uint*)(Xh + ((size_t)b * SEQ + s0 + p) * DMODEL) + u;
    float a0 = 0.f, a1 = 0.f;
    #pragma unroll 8
    for (int s = 0; s < PCHUNK; s += 2) {
        uint v   = xp[(size_t)s * (DMODEL / 2)];
        float ws = wl[s + p];
        a0 = fmaf(__uint_as_float(v << 16), ws, a0);
        a1 = fmaf(__uint_as_float(v & 0xFFFF0000u), ws, a1);
    }
    accs[t] = make_float2(a0, a1);
    __syncthreads();
    if (t < 256) {
        float2 x0 = accs[t], x1 = accs[t + 256];
        *(float2*)&partials[((size_t)sc * BATCH + b) * DMODEL + 2 * t] =
            make_float2(x0.x + x1.x, x0.y + x1.y);
    }
}

// K3b: out[b][f] = sum_sc partials[sc][b][f]
__global__ __launch_bounds__(512)
void pool_reduce_kernel(const float* __restrict__ partials, float* __restrict__ out) {
    int i = blockIdx.x * 512 + threadIdx.x;   // 32768
    float s = 0.f;
    #pragma unroll
    for (int c = 0; c < 8; ++c)
        s += partials[(size_t)c * BATCH * DMODEL + i];
    out[i] = s;
}

// fallback fp32 pool (if ws too small): needs memset + atomics
__global__ __launch_bounds__(512)
void pool_fp32_kernel(const float* __restrict__ X, const float* __restrict__ w,
                      float* __restrict__ out) {
    __shared__ float wl[PCHUNK];
    const int b  = blockIdx.y;
    const int sc = blockIdx.x;
    const int f  = threadIdx.x;
    const int s0 = sc * PCHUNK;
    if (f < PCHUNK) wl[f] = w[(size_t)b * SEQ + s0 + f];
    __syncthreads();
    const float* xp = X + ((size_t)b * SEQ + s0) * DMODEL + f;
    float a0 = 0.f, a1 = 0.f, a2 = 0.f, a3 = 0.f;
    #pragma unroll 4
    for (int s = 0; s < PCHUNK; s += 4) {
        a0 = fmaf(xp[(size_t)(s + 0) * DMODEL], wl[s + 0], a0);
        a1 = fmaf(xp[(size_t)(s + 1) * DMODEL], wl[s + 1], a1);
        a2 = fmaf(xp[(size_t)(s + 2) * DMODEL], wl[s + 2], a2);
        a3 = fmaf(xp[(size_t)(s + 3) * DMODEL], wl[s + 3], a3);
    }
    atomicAdd(&out[b * DMODEL + f], (a0 + a1) + (a2 + a3));
}

extern "C" void kernel_launch(void* const* d_in, const int* in_sizes, int n_in,
                              void* d_out, int out_size, void* d_ws, size_t ws_size,
                              hipStream_t stream) {
    const float* X  = (const float*)d_in[0];
    const float* Wa = (const float*)d_in[1];
    const float* ba = (const float*)d_in[2];
    const float* ae = (const float*)d_in[3];
    float* out  = (float*)d_out;
    float* feat = out;                       // [64][512]
    float* wgt  = out + BATCH * DMODEL;      // [64][2048]; z pre-softmax

    ushort* wa_cvt = (ushort*)d_ws;          // 512 KB
    const bool big_ws = ws_size >= WS_NEED;
    ushort* Xh      = big_ws ? (ushort*)((char*)d_ws + XH_OFF)  : nullptr;
    float* partials = big_ws ? (float*)((char*)d_ws + PART_OFF) : nullptr;

    wa_convert_kernel<<<ATT * DMODEL / 256, 256, 0, stream>>>(Wa, wa_cvt);
    scores_mfma_kernel<<<M_TOTAL / MT, 512, 0, stream>>>(X, wa_cvt, ba, ae, wgt, Xh);
    softmax_kernel<<<BATCH, 256, 0, stream>>>(wgt);
    if (big_ws) {
        pool_bf16_kernel<<<dim3(SEQ / PCHUNK, BATCH), 512, 0, stream>>>(Xh, wgt, partials);
        pool_reduce_kernel<<<BATCH * DMODEL / 512, 512, 0, stream>>>(partials, feat);
    } else {
        hipMemsetAsync(feat, 0, BATCH * DMODEL * sizeof(float), stream);
        pool_fp32_kernel<<<dim3(SEQ / PCHUNK, BATCH), 512, 0, stream>>>(X, wgt, feat);
    }
}